// Round 2
// baseline (45.437 us; speedup 1.0000x reference)
//
#include <hip/hip_runtime.h>

// DGCRNN forward, analytically reduced:
//   r = robot MLP embedding [B,64]; S = r + sum_humans h (h = human MLP [B,63,64])
//   out[b,o] = sum_f r[f]*Ar[f,o] + S[f]*As[f,o] + cheb_b[o]
//   Ar = W0 + W1/63 + (2/3969 - 1)*W2,  As = -W1/63 + (124/3969)*W2
// (complete digraph N=64: deg=63, edge w=-1/63 -> prop(x)=(x - S)/63, sum prop = -S)

#define BDIM 256

__global__ __launch_bounds__(256) void dgcrnn_fused(
    const float* __restrict__ robot_x,  // [B,1,9]
    const float* __restrict__ human_x,  // [B,63,5]
    const float* __restrict__ wr1, const float* __restrict__ wr1_b,   // [9,128],[128]
    const float* __restrict__ wr2, const float* __restrict__ wr2_b,   // [128,64],[64]
    const float* __restrict__ wh1, const float* __restrict__ wh1_b,   // [5,128],[128]
    const float* __restrict__ wh2, const float* __restrict__ wh2_b,   // [128,64],[64]
    const float* __restrict__ cw,  const float* __restrict__ cb,      // [3,64,64],[64]
    float* __restrict__ out)                                          // [B,64]
{
    __shared__ float x_lds[324];        // [0..8]=robot row, [9..323]=humans [63][5]
    __shared__ float h1[64 * 129];      // layer-1 activations, pad 129 (bank-free)
    __shared__ float part[4 * 64];      // robot partials, later output partials
    __shared__ float hsum[64];
    __shared__ float r_s[64];
    __shared__ float s_s[64];

    const int t    = threadIdx.x;
    const int b    = blockIdx.x;
    const int lane = t & 63;
    const int wv   = t >> 6;

    // ---- phase 0: stage per-batch inputs (324 > 256 threads -> strided loop!) ----
    for (int i = t; i < 324; i += BDIM) {
        x_lds[i] = (i < 9) ? robot_x[b * 9 + i]
                           : human_x[b * 315 + (i - 9)];
    }
    __syncthreads();

    // ---- phase 1: layer-1 hidden for all 64 nodes (node 0 = robot) ----
    for (int e = t; e < 64 * 128; e += BDIM) {
        int node = e >> 7, k = e & 127;
        float a;
        if (node == 0) {
            a = wr1_b[k];
            #pragma unroll
            for (int i = 0; i < 9; ++i) a = fmaf(x_lds[i], wr1[i * 128 + k], a);
        } else {
            a = wh1_b[k];
            const float* xp = &x_lds[9 + (node - 1) * 5];
            #pragma unroll
            for (int i = 0; i < 5; ++i) a = fmaf(xp[i], wh1[i * 128 + k], a);
        }
        h1[node * 129 + k] = fmaxf(a, 0.f);
    }
    __syncthreads();

    // ---- phase 2a: robot layer-2 partial sums (thread = (o, k-quarter)) ----
    {
        int o = t & 63, q = t >> 6;
        float rp = 0.f;
        #pragma unroll 8
        for (int j = 0; j < 32; ++j) {
            int k = q * 32 + j;
            rp = fmaf(h1[k], wr2[k * 64 + o], rp);   // h1 row 0 = robot (broadcast)
        }
        part[q * 64 + o] = rp;
    }

    // ---- phase 2b: humans layer-2, lane = node, wave owns 16 output cols ----
    {
        const int ob = wv * 16;
        const float* w2   = wh2 + ob;          // wave-uniform -> s_load path
        const float* hrow = &h1[lane * 129];   // (lane+k)%32 banks, conflict-free
        float acc[16];
        #pragma unroll
        for (int oo = 0; oo < 16; ++oo) acc[oo] = 0.f;
        for (int k = 0; k < 128; ++k) {
            float hv = hrow[k];
            #pragma unroll
            for (int oo = 0; oo < 16; ++oo)
                acc[oo] = fmaf(hv, w2[k * 64 + oo], acc[oo]);
        }
        #pragma unroll
        for (int oo = 0; oo < 16; ++oo) {
            // lane 0 is the robot's h1 row -> masked out of the human sum
            float c = (lane == 0) ? 0.f : fmaxf(acc[oo] + wh2_b[ob + oo], 0.f);
            #pragma unroll
            for (int m = 1; m < 64; m <<= 1) c += __shfl_xor(c, m, 64);
            if (lane == 0) hsum[ob + oo] = c;
        }
    }
    __syncthreads();

    // ---- phase 3: finalize r and S = r + sum_humans ----
    if (t < 64) {
        float r = part[t] + part[64 + t] + part[128 + t] + part[192 + t] + wr2_b[t];
        r = fmaxf(r, 0.f);
        r_s[t] = r;
        s_s[t] = r + hsum[t];
    }
    __syncthreads();

    // ---- phase 4: out = r @ Ar + S @ As + cb, Cheb weights folded on the fly ----
    {
        const float c1 = 1.0f / 63.0f;
        const float c2 = 2.0f / 3969.0f - 1.0f;
        const float c3 = 124.0f / 3969.0f;
        int o = t & 63, q = t >> 6;
        float a = 0.f;
        #pragma unroll 4
        for (int f = q * 16; f < q * 16 + 16; ++f) {
            float rv = r_s[f], sv = s_s[f];
            float w0 = cw[f * 64 + o];
            float w1 = cw[4096 + f * 64 + o];
            float w2 = cw[8192 + f * 64 + o];
            a += rv * (w0 + c1 * w1 + c2 * w2) + sv * (c3 * w2 - c1 * w1);
        }
        part[q * 64 + o] = a;   // part[] last read in phase 3, sync'ed above
    }
    __syncthreads();
    if (t < 64)
        out[b * 64 + t] = part[t] + part[64 + t] + part[128 + t] + part[192 + t] + cb[t];
}

extern "C" void kernel_launch(void* const* d_in, const int* in_sizes, int n_in,
                              void* d_out, int out_size, void* d_ws, size_t ws_size,
                              hipStream_t stream) {
    const float* robot_x = (const float*)d_in[0];
    const float* human_x = (const float*)d_in[1];
    // d_in[2] = edge_index (int32) -- graph is the fixed complete digraph; unused.
    const float* wr1   = (const float*)d_in[3];
    const float* wr1_b = (const float*)d_in[4];
    const float* wr2   = (const float*)d_in[5];
    const float* wr2_b = (const float*)d_in[6];
    const float* wh1   = (const float*)d_in[7];
    const float* wh1_b = (const float*)d_in[8];
    const float* wh2   = (const float*)d_in[9];
    const float* wh2_b = (const float*)d_in[10];
    const float* cw    = (const float*)d_in[11];
    const float* cb    = (const float*)d_in[12];
    float* out = (float*)d_out;

    dgcrnn_fused<<<512, BDIM, 0, stream>>>(robot_x, human_x,
                                           wr1, wr1_b, wr2, wr2_b,
                                           wh1, wh1_b, wh2, wh2_b,
                                           cw, cb, out);
}

// Round 3
// 19.178 us; speedup vs baseline: 2.3692x; 2.3692x over previous
//
#include <hip/hip_runtime.h>

// DGCRNN forward, analytically reduced:
//   r = robot MLP embedding [B,64]; S = r + sum_humans h (h = human MLP [B,63,64])
//   out[b,o] = sum_f r[f]*Ar[f,o] + S[f]*As[f,o] + cheb_b[o]
//   Ar = W0 + W1/63 + (2/3969 - 1)*W2,  As = -W1/63 + (124/3969)*W2
// (complete digraph N=64: deg=63, edge w=-1/63 -> prop(x)=(x - S)/63, sum prop = -S)
//
// R2 -> R3: kernel was VMEM-issue-bound (VALUBusy 14%): lane-redundant global
// weight loads in the hot loops. Now: phase-1 weights hoisted to regs (k fixed
// per thread), phase-2b weights via readfirstlane-uniform pointer -> s_load.

#define BDIM 256

__global__ __launch_bounds__(256) void dgcrnn_fused(
    const float* __restrict__ robot_x,  // [B,1,9]
    const float* __restrict__ human_x,  // [B,63,5]
    const float* __restrict__ wr1, const float* __restrict__ wr1_b,   // [9,128],[128]
    const float* __restrict__ wr2, const float* __restrict__ wr2_b,   // [128,64],[64]
    const float* __restrict__ wh1, const float* __restrict__ wh1_b,   // [5,128],[128]
    const float* __restrict__ wh2, const float* __restrict__ wh2_b,   // [128,64],[64]
    const float* __restrict__ cw,  const float* __restrict__ cb,      // [3,64,64],[64]
    float* __restrict__ out)                                          // [B,64]
{
    __shared__ float x_lds[324];        // [0..8]=robot row, [9..323]=humans [63][5]
    __shared__ float h1[64 * 129];      // layer-1 activations, pad 129 (bank-free)
    __shared__ float part[4 * 64];      // robot partials, later output partials
    __shared__ float hp[64 * 8];        // human-sum 8-lane-group partials
    __shared__ float r_s[64];
    __shared__ float s_s[64];

    const int t    = threadIdx.x;
    const int b    = blockIdx.x;
    const int lane = t & 63;
    const int wv   = t >> 6;

    // ---- phase 0: stage per-batch inputs ----
    for (int i = t; i < 324; i += BDIM)
        x_lds[i] = (i < 9) ? robot_x[b * 9 + i] : human_x[b * 315 + (i - 9)];
    __syncthreads();

    // ---- phase 1: layer-1. k fixed per thread; weights hoisted to registers.
    // waves 0,1 (half=0): nodes 0,2,..,62 ; waves 2,3 (half=1): nodes 1,3,..,63
    {
        const int k    = t & 127;
        const int half = t >> 7;              // wave-uniform
        float wh[5], wr[9];
        #pragma unroll
        for (int i = 0; i < 5; ++i) wh[i] = wh1[i * 128 + k];
        const float bh = wh1_b[k];
        float br = 0.f;
        if (half == 0) {                      // wave-uniform branch
            #pragma unroll
            for (int i = 0; i < 9; ++i) wr[i] = wr1[i * 128 + k];
            br = wr1_b[k];
        }
        #pragma unroll 4
        for (int n = half; n < 64; n += 2) {  // n wave-uniform -> LDS broadcasts
            float a;
            if (n == 0) {
                a = br;
                #pragma unroll
                for (int i = 0; i < 9; ++i) a = fmaf(x_lds[i], wr[i], a);
            } else {
                a = bh;
                const float* xp = &x_lds[9 + (n - 1) * 5];
                #pragma unroll
                for (int i = 0; i < 5; ++i) a = fmaf(xp[i], wh[i], a);
            }
            h1[n * 129 + k] = fmaxf(a, 0.f);
        }
    }
    __syncthreads();

    // ---- phase 2a: robot layer-2 partials (thread = (o, k-quarter)) ----
    {
        const int o = t & 63, q = t >> 6;
        float rp = 0.f;
        #pragma unroll
        for (int j = 0; j < 32; ++j) {
            int k = q * 32 + j;
            rp = fmaf(h1[k], wr2[k * 64 + o], rp);  // h1 row0 broadcast; wr2 coalesced
        }
        part[q * 64 + o] = rp;
    }

    // ---- phase 2b: humans layer-2, lane = node, wave owns 16 output cols.
    // Weight pointer made provably scalar -> s_load_dwordx16 per k (SGPR-operand FMAs).
    {
        const int ob = __builtin_amdgcn_readfirstlane(wv) * 16;
        const float* __restrict__ w2 = wh2 + ob;
        const float* hrow = &h1[lane * 129];   // banks (lane+k)%32: 2-way = free
        float acc[16];
        #pragma unroll
        for (int oo = 0; oo < 16; ++oo) acc[oo] = 0.f;
        #pragma unroll 4
        for (int k = 0; k < 128; ++k) {
            const float hv = hrow[k];
            #pragma unroll
            for (int oo = 0; oo < 16; ++oo)
                acc[oo] = fmaf(hv, w2[k * 64 + oo], acc[oo]);
        }
        // bias + relu, robot row masked out, 8-lane-group reduce -> LDS partials
        #pragma unroll
        for (int oo = 0; oo < 16; ++oo) {
            float c = (lane == 0) ? 0.f : fmaxf(acc[oo] + wh2_b[ob + oo], 0.f);
            c += __shfl_xor(c, 1, 64);
            c += __shfl_xor(c, 2, 64);
            c += __shfl_xor(c, 4, 64);
            if ((lane & 7) == 0) hp[(ob + oo) * 8 + (lane >> 3)] = c;
        }
    }
    __syncthreads();

    // ---- phase 3: finalize r and S = r + sum_humans ----
    if (t < 64) {
        const float* hq = &hp[t * 8];
        float hs = ((hq[0] + hq[1]) + (hq[2] + hq[3])) + ((hq[4] + hq[5]) + (hq[6] + hq[7]));
        float r = part[t] + part[64 + t] + part[128 + t] + part[192 + t] + wr2_b[t];
        r = fmaxf(r, 0.f);
        r_s[t] = r;
        s_s[t] = r + hs;
    }
    __syncthreads();

    // ---- phase 4: out = r @ Ar + S @ As + cb, Cheb weights folded on the fly ----
    {
        const float c1 = 1.0f / 63.0f;
        const float c2 = 2.0f / 3969.0f - 1.0f;
        const float c3 = 124.0f / 3969.0f;
        const int o = t & 63, q = t >> 6;
        float a = 0.f;
        #pragma unroll
        for (int j = 0; j < 16; ++j) {
            int f = q * 16 + j;                    // wave-uniform -> r_s/s_s broadcast
            float rv = r_s[f], sv = s_s[f];
            float w0 = cw[f * 64 + o];             // coalesced
            float w1 = cw[4096 + f * 64 + o];
            float w2v = cw[8192 + f * 64 + o];
            a += rv * (w0 + c1 * w1 + c2 * w2v) + sv * (c3 * w2v - c1 * w1);
        }
        part[q * 64 + o] = a;
    }
    __syncthreads();
    if (t < 64)
        out[b * 64 + t] = part[t] + part[64 + t] + part[128 + t] + part[192 + t] + cb[t];
}

extern "C" void kernel_launch(void* const* d_in, const int* in_sizes, int n_in,
                              void* d_out, int out_size, void* d_ws, size_t ws_size,
                              hipStream_t stream) {
    const float* robot_x = (const float*)d_in[0];
    const float* human_x = (const float*)d_in[1];
    // d_in[2] = edge_index (int32) -- graph is the fixed complete digraph; unused.
    const float* wr1   = (const float*)d_in[3];
    const float* wr1_b = (const float*)d_in[4];
    const float* wr2   = (const float*)d_in[5];
    const float* wr2_b = (const float*)d_in[6];
    const float* wh1   = (const float*)d_in[7];
    const float* wh1_b = (const float*)d_in[8];
    const float* wh2   = (const float*)d_in[9];
    const float* wh2_b = (const float*)d_in[10];
    const float* cw    = (const float*)d_in[11];
    const float* cb    = (const float*)d_in[12];
    float* out = (float*)d_out;

    dgcrnn_fused<<<512, BDIM, 0, stream>>>(robot_x, human_x,
                                           wr1, wr1_b, wr2, wr2_b,
                                           wh1, wh1_b, wh2, wh2_b,
                                           cw, cb, out);
}

// Round 4
// 12.679 us; speedup vs baseline: 3.5837x; 1.5126x over previous
//
#include <hip/hip_runtime.h>

// DGCRNN forward, analytically reduced (complete digraph N=64, deg=63):
//   prop(x) = (x - S)/63 with S = column-sum; only robot node kept =>
//   out[b,o] = sum_f r[f]*Ar[f,o] + S[f]*As[f,o] + cb[o]
//   Ar = W0 + W1/63 + (2/3969 - 1)*W2,  As = -W1/63 + (124/3969)*W2
//
// R3 -> R4: humans layer-2 GEMM ([64x128]@[128x64] per batch) moved to MFMA
// (mfma_f32_16x16x32_bf16, 16 per wave) instead of 2048 VALU FMA/thread.
// h1 written as pre-packed bf16 A-fragments (linear lane order, conflict-free);
// wh2 transposed+cvt to XOR-swizzled bf16 LDS tile for B-fragments.

#define BDIM 256

typedef __attribute__((ext_vector_type(8))) short bf16x8;
typedef __attribute__((ext_vector_type(4))) float f32x4;

static __device__ __forceinline__ unsigned short f2bf(float f) {  // RNE
    unsigned int u = __float_as_uint(f);
    u += 0x7FFF + ((u >> 16) & 1);
    return (unsigned short)(u >> 16);
}

__global__ __launch_bounds__(256) void dgcrnn_mfma(
    const float* __restrict__ robot_x,  // [B,1,9]
    const float* __restrict__ human_x,  // [B,63,5]
    const float* __restrict__ wr1, const float* __restrict__ wr1_b,   // [9,128],[128]
    const float* __restrict__ wr2, const float* __restrict__ wr2_b,   // [128,64],[64]
    const float* __restrict__ wh1, const float* __restrict__ wh1_b,   // [5,128],[128]
    const float* __restrict__ wh2, const float* __restrict__ wh2_b,   // [128,64],[64]
    const float* __restrict__ cw,  const float* __restrict__ cb,      // [3,64,64],[64]
    float* __restrict__ out)                                          // [B,64]
{
    __shared__ float x_lds[324];       // robot row [0..8], humans [63][5]
    __shared__ float wh1_l[768];       // [6][128]: rows 0-4 wh1, row 5 bias
    __shared__ float wr1_l[1280];      // [10][128]: rows 0-8 wr1, row 9 bias
    __shared__ float wh2b_l[64];
    __shared__ float rrow[128];        // robot h1 (fp32, post-relu)
    __shared__ unsigned int wh2T[4096];// wh2^T bf16x2, XOR-swizzled [o][k-words]
    __shared__ short fragA[8192];      // bf16 A-frags, slot-linear (16 KB)
    __shared__ float part[256];        // robot l2 partials, later out partials
    __shared__ float hpart[256];       // per-wave human-sum partials [w][o]
    __shared__ float r_s[64], s_s[64];

    const int t = threadIdx.x;
    const int b = blockIdx.x;
    const int l = t & 63;
    const int w = t >> 6;

    // ---- stage: inputs + all small weights (coalesced), wh2 -> bf16 transpose ----
    for (int i = t; i < 324; i += BDIM)
        x_lds[i] = (i < 9) ? robot_x[b * 9 + i] : human_x[b * 315 + (i - 9)];
    for (int i = t; i < 768; i += BDIM)
        wh1_l[i] = (i < 640) ? wh1[i] : wh1_b[i - 640];
    for (int i = t; i < 1280; i += BDIM)
        wr1_l[i] = (i < 1152) ? wr1[i] : wr1_b[i - 1152];
    if (t < 64) wh2b_l[t] = wh2_b[t];
    for (int rr = 0; rr < 16; ++rr) {           // wh2[k][o] -> wh2T[o][k] bf16
        int p  = rr * 256 + t;
        int o  = p & 63, kp = p >> 6;           // kp = k/2
        float v0 = wh2[(2 * kp) * 64 + o];      // coalesced in o
        float v1 = wh2[(2 * kp + 1) * 64 + o];
        unsigned int wv = (unsigned int)f2bf(v0) | ((unsigned int)f2bf(v1) << 16);
        wh2T[o * 64 + (kp ^ ((o & 15) << 2))] = wv;   // XOR-swizzle, bijective
    }
    __syncthreads();

    // ---- phase 1: layer-1. Humans -> bf16 A-fragments; robot -> rrow fp32.
    // slot = mt*256 + kt*64 + kb*16 + r ; A-frag lane = kb*16 + r holds
    // A[row=16*mt+r][k = 32*kt+8*kb+j], j=0..7 (contiguous-k layout).
    #pragma unroll
    for (int s = 0; s < 4; ++s) {
        int slot = s * 256 + t;
        int row  = ((slot >> 8) << 4) | (slot & 15);
        int k0   = ((slot >> 6) & 3) * 32 + ((slot >> 4) & 3) * 8;
        bf16x8 v;
        #pragma unroll
        for (int j = 0; j < 8; ++j) v[j] = 0;
        if (row != 63) {                        // row 63 = zero pad (64th human absent)
            float a8[8];
            #pragma unroll
            for (int j = 0; j < 8; ++j) a8[j] = wh1_l[640 + k0 + j];  // bias
            #pragma unroll
            for (int i = 0; i < 5; ++i) {
                float xv = x_lds[9 + row * 5 + i];
                #pragma unroll
                for (int j = 0; j < 8; ++j)
                    a8[j] = fmaf(xv, wh1_l[i * 128 + k0 + j], a8[j]);
            }
            #pragma unroll
            for (int j = 0; j < 8; ++j) v[j] = (short)f2bf(fmaxf(a8[j], 0.f));
        }
        *reinterpret_cast<bf16x8*>(&fragA[slot * 8]) = v;   // linear: conflict-free
    }
    if (t < 128) {                              // robot h1 (fp32 for VALU layer-2)
        float a = wr1_l[1152 + t];
        #pragma unroll
        for (int i = 0; i < 9; ++i) a = fmaf(x_lds[i], wr1_l[i * 128 + t], a);
        rrow[t] = fmaxf(a, 0.f);
    }
    __syncthreads();

    // ---- phase 2a: robot layer-2 partials on VALU (thread = (o, k-quarter)) ----
    {
        int o = t & 63, q = t >> 6;
        float rp = 0.f;
        #pragma unroll
        for (int j = 0; j < 32; ++j) {
            int k = q * 32 + j;
            rp = fmaf(rrow[k], wr2[k * 64 + o], rp);  // rrow broadcast; wr2 coalesced
        }
        part[q * 64 + o] = rp;
    }

    // ---- phase 2b: humans layer-2 via MFMA. Wave w owns M-tile (nodes 16w..16w+15).
    {
        const int c = l & 15, g = l >> 4;
        bf16x8 af[4];
        #pragma unroll
        for (int kt = 0; kt < 4; ++kt)
            af[kt] = *reinterpret_cast<const bf16x8*>(&fragA[((w * 4 + kt) * 64 + l) * 8]);
        #pragma unroll
        for (int nt = 0; nt < 4; ++nt) {
            const int o = nt * 16 + c;
            f32x4 acc = {0.f, 0.f, 0.f, 0.f};
            #pragma unroll
            for (int kt = 0; kt < 4; ++kt) {
                int kw0 = kt * 16 + g * 4;      // word offset of 8 contiguous bf16
                bf16x8 bfv = *reinterpret_cast<const bf16x8*>(
                    &wh2T[o * 64 + (kw0 ^ (c << 2))]);
                acc = __builtin_amdgcn_mfma_f32_16x16x32_bf16(af[kt], bfv, acc, 0, 0, 0);
            }
            // epilogue: relu(D+bias), mask pad row, sum 16 rows of this M-tile
            float bias = wh2b_l[o];
            float s4 = 0.f;
            #pragma unroll
            for (int reg = 0; reg < 4; ++reg) {
                int node = w * 16 + g * 4 + reg;     // C/D: row=(lane>>4)*4+reg
                float hv = fmaxf(acc[reg] + bias, 0.f);
                s4 += (node == 63) ? 0.f : hv;
            }
            s4 += __shfl_xor(s4, 16, 64);
            s4 += __shfl_xor(s4, 32, 64);
            if (g == 0) hpart[w * 64 + o] = s4;
        }
    }
    __syncthreads();

    // ---- phase 3: r = relu(robot l2), S = r + human sum ----
    if (t < 64) {
        float hs = hpart[t] + hpart[64 + t] + hpart[128 + t] + hpart[192 + t];
        float r  = part[t] + part[64 + t] + part[128 + t] + part[192 + t] + wr2_b[t];
        r = fmaxf(r, 0.f);
        r_s[t] = r;
        s_s[t] = r + hs;
    }
    __syncthreads();

    // ---- phase 4: out = r @ Ar + S @ As + cb (Cheb weights folded on the fly) ----
    {
        const float c1 = 1.0f / 63.0f;
        const float c2 = 2.0f / 3969.0f - 1.0f;
        const float c3 = 124.0f / 3969.0f;
        const int o = t & 63, q = t >> 6;
        float a = 0.f;
        #pragma unroll
        for (int j = 0; j < 16; ++j) {
            int f = q * 16 + j;                  // wave-uniform -> LDS broadcast
            float rv = r_s[f], sv = s_s[f];
            float w0 = cw[f * 64 + o];
            float w1 = cw[4096 + f * 64 + o];
            float w2v = cw[8192 + f * 64 + o];
            a += rv * (w0 + c1 * w1 + c2 * w2v) + sv * (c3 * w2v - c1 * w1);
        }
        part[q * 64 + o] = a;
    }
    __syncthreads();
    if (t < 64)
        out[b * 64 + t] = part[t] + part[64 + t] + part[128 + t] + part[192 + t] + cb[t];
}

extern "C" void kernel_launch(void* const* d_in, const int* in_sizes, int n_in,
                              void* d_out, int out_size, void* d_ws, size_t ws_size,
                              hipStream_t stream) {
    const float* robot_x = (const float*)d_in[0];
    const float* human_x = (const float*)d_in[1];
    // d_in[2] = edge_index (int32) -- fixed complete digraph; unused.
    const float* wr1   = (const float*)d_in[3];
    const float* wr1_b = (const float*)d_in[4];
    const float* wr2   = (const float*)d_in[5];
    const float* wr2_b = (const float*)d_in[6];
    const float* wh1   = (const float*)d_in[7];
    const float* wh1_b = (const float*)d_in[8];
    const float* wh2   = (const float*)d_in[9];
    const float* wh2_b = (const float*)d_in[10];
    const float* cw    = (const float*)d_in[11];
    const float* cb    = (const float*)d_in[12];
    float* out = (float*)d_out;

    dgcrnn_mfma<<<512, BDIM, 0, stream>>>(robot_x, human_x,
                                          wr1, wr1_b, wr2, wr2_b,
                                          wh1, wh1_b, wh2, wh2_b,
                                          cw, cb, out);
}

// Round 5
// 12.419 us; speedup vs baseline: 3.6586x; 1.0209x over previous
//
#include <hip/hip_runtime.h>

// DGCRNN forward, analytically reduced (complete digraph N=64, deg=63):
//   prop(x) = (x - S)/63 with S = column-sum; only robot node kept =>
//   out[b,o] = sum_f r[f]*Ar[f,o] + S[f]*As[f,o] + cb[o]
//   Ar = W0 + W1/63 + (2/3969 - 1)*W2,  As = -W1/63 + (124/3969)*W2
//
// R4 -> R5: occupancy 2->4 waves/SIMD (512-thr blocks, 8 waves/batch);
// per-thread VMEM ~120 scalar -> ~20 dwordx4 via o-quad layout; wr2/cw
// loads hoisted to kernel entry so L2 latency hides under staging/layer-1.

#define BDIM 512

typedef __attribute__((ext_vector_type(8))) short bf16x8;
typedef __attribute__((ext_vector_type(4))) float f32x4;

static __device__ __forceinline__ unsigned short f2bf(float f) {  // RNE
    unsigned int u = __float_as_uint(f);
    u += 0x7FFF + ((u >> 16) & 1);
    return (unsigned short)(u >> 16);
}

__global__ __launch_bounds__(512, 4) void dgcrnn_mfma(
    const float* __restrict__ robot_x,  // [B,1,9]
    const float* __restrict__ human_x,  // [B,63,5]
    const float* __restrict__ wr1, const float* __restrict__ wr1_b,   // [9,128],[128]
    const float* __restrict__ wr2, const float* __restrict__ wr2_b,   // [128,64],[64]
    const float* __restrict__ wh1, const float* __restrict__ wh1_b,   // [5,128],[128]
    const float* __restrict__ wh2, const float* __restrict__ wh2_b,   // [128,64],[64]
    const float* __restrict__ cw,  const float* __restrict__ cb,      // [3,64,64],[64]
    float* __restrict__ out)                                          // [B,64]
{
    __shared__ float x_lds[324];                       // robot [0..8], humans [63][5]
    __shared__ float wh1_l[768];                       // rows 0-4 wh1, row 5 bias
    __shared__ float wr1_l[1280];                      // rows 0-8 wr1, row 9 bias
    __shared__ float wh2b_l[64];
    __shared__ float rrow[128];                        // robot h1 (fp32)
    __shared__ __align__(16) unsigned int wh2T[4096];  // wh2^T bf16x2, XOR-swizzled
    __shared__ __align__(16) short fragA[8192];        // bf16 A-frags, slot-linear
    __shared__ __align__(16) float rp_lds[2048];       // [32][64] partials (2a, then 4)
    __shared__ float hpart[256];                       // [mt][o] human-sum partials
    __shared__ float r_s[64], s_s[64];

    const int t   = threadIdx.x;
    const int b   = blockIdx.x;
    const int l   = t & 63;
    const int w   = t >> 6;        // wave 0..7
    const int oq  = t & 15;
    const int o0  = oq * 4;        // o-quad base
    const int g16 = t >> 4;        // 0..31

    // ---- hoisted global loads: latency hides under staging + layer-1 ----
    float4 wr2q[4];                             // wr2[4*g16+j][o0..o0+3]
    #pragma unroll
    for (int j = 0; j < 4; ++j)
        wr2q[j] = *(const float4*)&wr2[(g16 * 4 + j) * 64 + o0];
    float4 cwq[2][3];                           // cw[k][2*g16+ff][o0..o0+3]
    #pragma unroll
    for (int ff = 0; ff < 2; ++ff)
        #pragma unroll
        for (int k = 0; k < 3; ++k)
            cwq[ff][k] = *(const float4*)&cw[k * 4096 + (g16 * 2 + ff) * 64 + o0];

    // ---- stage: inputs + layer-1 weights; wh2 -> bf16 transposed swizzled tile ----
    for (int i = t; i < 324; i += BDIM)
        x_lds[i] = (i < 9) ? robot_x[b * 9 + i] : human_x[b * 315 + (i - 9)];
    for (int i = t; i < 768; i += BDIM)
        wh1_l[i] = (i < 640) ? wh1[i] : wh1_b[i - 640];
    for (int i = t; i < 1280; i += BDIM)
        wr1_l[i] = (i < 1152) ? wr1[i] : wr1_b[i - 1152];
    if (t < 64) wh2b_l[t] = wh2_b[t];
    #pragma unroll
    for (int kk = 0; kk < 2; ++kk) {            // thread covers kp = 2*g16 + kk
        int kp = g16 * 2 + kk;                  // k-pair index 0..63
        float4 e = *(const float4*)&wh2[(2 * kp) * 64 + o0];      // k even row
        float4 d = *(const float4*)&wh2[(2 * kp + 1) * 64 + o0];  // k odd row
        #pragma unroll
        for (int c = 0; c < 4; ++c) {
            int o = o0 + c;
            unsigned int wv = (unsigned int)f2bf((&e.x)[c])
                            | ((unsigned int)f2bf((&d.x)[c]) << 16);
            wh2T[o * 64 + (kp ^ ((o & 15) << 2))] = wv;   // bijective XOR swizzle
        }
    }
    __syncthreads();

    // ---- phase 1: layer-1. Humans -> bf16 A-fragments; robot -> rrow fp32.
    // slot = mt*256 + kt*64 + kb*16 + r ; lane kb*16+r holds A[16mt+r][32kt+8kb+j]
    #pragma unroll
    for (int s = 0; s < 2; ++s) {
        int slot = s * 512 + t;
        int row  = ((slot >> 8) << 4) | (slot & 15);
        int k0   = ((slot >> 6) & 3) * 32 + ((slot >> 4) & 3) * 8;
        bf16x8 v;
        #pragma unroll
        for (int j = 0; j < 8; ++j) v[j] = 0;
        if (row != 63) {                        // row 63 = zero pad
            float a8[8];
            #pragma unroll
            for (int j = 0; j < 8; ++j) a8[j] = wh1_l[640 + k0 + j];
            #pragma unroll
            for (int i = 0; i < 5; ++i) {
                float xv = x_lds[9 + row * 5 + i];
                #pragma unroll
                for (int j = 0; j < 8; ++j)
                    a8[j] = fmaf(xv, wh1_l[i * 128 + k0 + j], a8[j]);
            }
            #pragma unroll
            for (int j = 0; j < 8; ++j) v[j] = (short)f2bf(fmaxf(a8[j], 0.f));
        }
        *reinterpret_cast<bf16x8*>(&fragA[slot * 8]) = v;
    }
    if (t < 128) {                              // robot h1
        float a = wr1_l[1152 + t];
        #pragma unroll
        for (int i = 0; i < 9; ++i) a = fmaf(x_lds[i], wr1_l[i * 128 + t], a);
        rrow[t] = fmaxf(a, 0.f);
    }
    __syncthreads();

    // ---- phase 2a: robot layer-2 partials from hoisted wr2 quads ----
    {
        float4 rp = {0.f, 0.f, 0.f, 0.f};
        #pragma unroll
        for (int j = 0; j < 4; ++j) {
            float hv = rrow[g16 * 4 + j];       // 4-way broadcast
            rp.x = fmaf(hv, wr2q[j].x, rp.x);
            rp.y = fmaf(hv, wr2q[j].y, rp.y);
            rp.z = fmaf(hv, wr2q[j].z, rp.z);
            rp.w = fmaf(hv, wr2q[j].w, rp.w);
        }
        *(float4*)&rp_lds[g16 * 64 + o0] = rp;
    }

    // ---- phase 2b: humans layer-2 via MFMA. wave w: mt = w>>1, o-half = w&1 ----
    {
        const int c = l & 15, g = l >> 4;
        const int mt = w >> 1;
        bf16x8 af[4];
        #pragma unroll
        for (int kt = 0; kt < 4; ++kt)
            af[kt] = *reinterpret_cast<const bf16x8*>(&fragA[((mt * 4 + kt) * 64 + l) * 8]);
        #pragma unroll
        for (int ni = 0; ni < 2; ++ni) {
            const int nt = (w & 1) * 2 + ni;
            const int o  = nt * 16 + c;
            f32x4 acc = {0.f, 0.f, 0.f, 0.f};
            #pragma unroll
            for (int kt = 0; kt < 4; ++kt) {
                int kw0 = kt * 16 + g * 4;
                bf16x8 bfv = *reinterpret_cast<const bf16x8*>(
                    &wh2T[o * 64 + (kw0 ^ (c << 2))]);
                acc = __builtin_amdgcn_mfma_f32_16x16x32_bf16(af[kt], bfv, acc, 0, 0, 0);
            }
            float bias = wh2b_l[o];
            float s4 = 0.f;
            #pragma unroll
            for (int reg = 0; reg < 4; ++reg) {
                int node = mt * 16 + g * 4 + reg;    // C/D: row=(lane>>4)*4+reg
                float hv = fmaxf(acc[reg] + bias, 0.f);
                s4 += (node == 63) ? 0.f : hv;
            }
            s4 += __shfl_xor(s4, 16, 64);
            s4 += __shfl_xor(s4, 32, 64);
            if (g == 0) hpart[mt * 64 + o] = s4;
        }
    }
    __syncthreads();

    // ---- phase 3: r = relu(robot l2), S = r + human sum ----
    if (t < 64) {
        float hs = hpart[t] + hpart[64 + t] + hpart[128 + t] + hpart[192 + t];
        float rsum = wr2_b[t];
        #pragma unroll
        for (int kg = 0; kg < 32; ++kg) rsum += rp_lds[kg * 64 + t];
        float r = fmaxf(rsum, 0.f);
        r_s[t] = r;
        s_s[t] = r + hs;
    }
    __syncthreads();

    // ---- phase 4: out = r @ Ar + S @ As + cb from hoisted cw quads ----
    {
        const float c1 = 1.0f / 63.0f;
        const float c2 = 2.0f / 3969.0f - 1.0f;
        const float c3 = 124.0f / 3969.0f;
        float4 a4 = {0.f, 0.f, 0.f, 0.f};
        #pragma unroll
        for (int ff = 0; ff < 2; ++ff) {
            int f = g16 * 2 + ff;
            float rv = r_s[f], sv = s_s[f];
            #pragma unroll
            for (int c = 0; c < 4; ++c) {
                float w0  = (&cwq[ff][0].x)[c];
                float w1  = (&cwq[ff][1].x)[c];
                float w2v = (&cwq[ff][2].x)[c];
                (&a4.x)[c] += rv * (w0 + c1 * w1 + c2 * w2v)
                            + sv * (c3 * w2v - c1 * w1);
            }
        }
        *(float4*)&rp_lds[g16 * 64 + o0] = a4;   // reuse rp_lds (read done in ph.3)
    }
    __syncthreads();
    if (t < 64) {
        float a = cb[t];
        #pragma unroll
        for (int kg = 0; kg < 32; ++kg) a += rp_lds[kg * 64 + t];
        out[b * 64 + t] = a;
    }
}

extern "C" void kernel_launch(void* const* d_in, const int* in_sizes, int n_in,
                              void* d_out, int out_size, void* d_ws, size_t ws_size,
                              hipStream_t stream) {
    const float* robot_x = (const float*)d_in[0];
    const float* human_x = (const float*)d_in[1];
    // d_in[2] = edge_index (int32) -- fixed complete digraph; unused.
    const float* wr1   = (const float*)d_in[3];
    const float* wr1_b = (const float*)d_in[4];
    const float* wr2   = (const float*)d_in[5];
    const float* wr2_b = (const float*)d_in[6];
    const float* wh1   = (const float*)d_in[7];
    const float* wh1_b = (const float*)d_in[8];
    const float* wh2   = (const float*)d_in[9];
    const float* wh2_b = (const float*)d_in[10];
    const float* cw    = (const float*)d_in[11];
    const float* cb    = (const float*)d_in[12];
    float* out = (float*)d_out;

    dgcrnn_mfma<<<512, BDIM, 0, stream>>>(robot_x, human_x,
                                          wr1, wr1_b, wr2, wr2_b,
                                          wh1, wh1_b, wh2, wh2_b,
                                          cw, cb, out);
}

// Round 6
// 11.973 us; speedup vs baseline: 3.7948x; 1.0372x over previous
//
#include <hip/hip_runtime.h>

// DGCRNN forward, analytically reduced (complete digraph N=64, deg=63):
//   prop(x) = (x - S)/63 with S = column-sum; only robot node kept =>
//   out[b,o] = sum_f r[f]*Ar[f,o] + S[f]*As[f,o] + cb[o]
//   Ar = W0 + W1/63 + (2/3969 - 1)*W2,  As = -W1/63 + (124/3969)*W2
//
// R5 -> R6: barrier chain 6 -> 4. wr2/wr1 hoisted to registers at entry;
// r/S reduction computed redundantly per thread (fuses phase 3 into 4);
// phase-4 partials alias fragA (dead after MFMA) to avoid a hazard barrier;
// cw loads issued after B1 so latency hides under MFMA + reduce phases.

#define BDIM 256

typedef __attribute__((ext_vector_type(8))) short bf16x8;
typedef __attribute__((ext_vector_type(4))) float f32x4;

static __device__ __forceinline__ unsigned short f2bf(float f) {  // RNE
    unsigned int u = __float_as_uint(f);
    u += 0x7FFF + ((u >> 16) & 1);
    return (unsigned short)(u >> 16);
}

__global__ __launch_bounds__(256, 2) void dgcrnn_mfma(
    const float* __restrict__ robot_x,  // [B,1,9]
    const float* __restrict__ human_x,  // [B,63,5]
    const float* __restrict__ wr1, const float* __restrict__ wr1_b,   // [9,128],[128]
    const float* __restrict__ wr2, const float* __restrict__ wr2_b,   // [128,64],[64]
    const float* __restrict__ wh1, const float* __restrict__ wh1_b,   // [5,128],[128]
    const float* __restrict__ wh2, const float* __restrict__ wh2_b,   // [128,64],[64]
    const float* __restrict__ cw,  const float* __restrict__ cb,      // [3,64,64],[64]
    float* __restrict__ out)                                          // [B,64]
{
    __shared__ float x_lds[324];                       // robot [0..8], humans [63][5]
    __shared__ float wh1_l[768];                       // rows 0-4 wh1, row 5 bias
    __shared__ float wh2b_l[64], wr2b_l[64], cb_l[64];
    __shared__ float rrow[128];                        // robot h1 (fp32)
    __shared__ __align__(16) unsigned int wh2T[4096];  // wh2^T bf16x2, XOR-swizzled
    __shared__ __align__(16) short fragA[8192];        // bf16 A-frags; later out_part
    __shared__ __align__(16) float rp_lds[1024];       // [16][64] robot l2 partials
    __shared__ float hpart[256];                       // [mt][o] human-sum partials

    const int t    = threadIdx.x;
    const int b    = blockIdx.x;
    const int l    = t & 63;
    const int w    = t >> 6;        // wave 0..3
    const int oq   = t & 15;
    const int o0   = oq * 4;
    const int fgrp = t >> 4;        // 0..15

    // ---- hoisted register loads (latency hides under staging) ----
    float4 wr2q[8];                                    // wr2[fgrp*8+j][o0..+3]
    #pragma unroll
    for (int j = 0; j < 8; ++j)
        wr2q[j] = *(const float4*)&wr2[(fgrp * 8 + j) * 64 + o0];
    float wr1c[9], wr1bb = 0.f;
    if (t < 128) {                                     // robot col t
        #pragma unroll
        for (int i = 0; i < 9; ++i) wr1c[i] = wr1[i * 128 + t];
        wr1bb = wr1_b[t];
    }

    // ---- stage: inputs + wh1 + small vecs; wh2 -> bf16 transposed swizzled ----
    for (int i = t; i < 324; i += BDIM)
        x_lds[i] = (i < 9) ? robot_x[b * 9 + i] : human_x[b * 315 + (i - 9)];
    for (int i = t; i < 768; i += BDIM)
        wh1_l[i] = (i < 640) ? wh1[i] : wh1_b[i - 640];
    if (t < 64) { wh2b_l[t] = wh2_b[t]; wr2b_l[t] = wr2_b[t]; cb_l[t] = cb[t]; }
    #pragma unroll
    for (int kk = 0; kk < 4; ++kk) {                   // k-pairs kp = fgrp*4+kk
        int kp = fgrp * 4 + kk;
        float4 e = *(const float4*)&wh2[(2 * kp) * 64 + o0];
        float4 d = *(const float4*)&wh2[(2 * kp + 1) * 64 + o0];
        #pragma unroll
        for (int c = 0; c < 4; ++c) {
            int o = o0 + c;
            unsigned int wv = (unsigned int)f2bf((&e.x)[c])
                            | ((unsigned int)f2bf((&d.x)[c]) << 16);
            wh2T[o * 64 + (kp ^ ((o & 15) << 2))] = wv;   // bijective XOR swizzle
        }
    }
    __syncthreads();                                   // B0

    // ---- phase 1: layer-1. Humans -> bf16 A-frags (k0 invariant across slots
    // for fixed t -> weights register-cached once); robot -> rrow fp32.
    {
        const int k0 = ((t >> 6) & 3) * 32 + ((t >> 4) & 3) * 8;
        float wv[5][8], bias8[8];
        #pragma unroll
        for (int j = 0; j < 8; ++j) bias8[j] = wh1_l[640 + k0 + j];
        #pragma unroll
        for (int i = 0; i < 5; ++i)
            #pragma unroll
            for (int j = 0; j < 8; ++j) wv[i][j] = wh1_l[i * 128 + k0 + j];
        #pragma unroll
        for (int s = 0; s < 4; ++s) {
            int slot = s * 256 + t;
            int row  = (s << 4) | (t & 15);            // human index, 63 = pad
            bf16x8 v;
            #pragma unroll
            for (int j = 0; j < 8; ++j) v[j] = 0;
            if (row != 63) {
                float a8[8];
                #pragma unroll
                for (int j = 0; j < 8; ++j) a8[j] = bias8[j];
                #pragma unroll
                for (int i = 0; i < 5; ++i) {
                    float xv = x_lds[9 + row * 5 + i];
                    #pragma unroll
                    for (int j = 0; j < 8; ++j) a8[j] = fmaf(xv, wv[i][j], a8[j]);
                }
                #pragma unroll
                for (int j = 0; j < 8; ++j) v[j] = (short)f2bf(fmaxf(a8[j], 0.f));
            }
            *reinterpret_cast<bf16x8*>(&fragA[slot * 8]) = v;
        }
    }
    if (t < 128) {                                     // robot h1 from hoisted regs
        float a = wr1bb;
        #pragma unroll
        for (int i = 0; i < 9; ++i) a = fmaf(x_lds[i], wr1c[i], a);
        rrow[t] = fmaxf(a, 0.f);
    }
    __syncthreads();                                   // B1

    // ---- phase 2b: humans layer-2 via MFMA. wave = mt (16 MFMA/wave) ----
    {
        const int c = l & 15, g = l >> 4, mt = w;
        bf16x8 af[4];
        #pragma unroll
        for (int kt = 0; kt < 4; ++kt)
            af[kt] = *reinterpret_cast<const bf16x8*>(&fragA[((mt * 4 + kt) * 64 + l) * 8]);
        #pragma unroll
        for (int nt = 0; nt < 4; ++nt) {
            const int o = nt * 16 + c;
            f32x4 acc = {0.f, 0.f, 0.f, 0.f};
            #pragma unroll
            for (int kt = 0; kt < 4; ++kt) {
                int kw0 = kt * 16 + g * 4;
                bf16x8 bfv = *reinterpret_cast<const bf16x8*>(
                    &wh2T[o * 64 + (kw0 ^ (c << 2))]);
                acc = __builtin_amdgcn_mfma_f32_16x16x32_bf16(af[kt], bfv, acc, 0, 0, 0);
            }
            float bias = wh2b_l[o];
            float s4 = 0.f;
            #pragma unroll
            for (int reg = 0; reg < 4; ++reg) {
                int node = mt * 16 + g * 4 + reg;      // C/D: row=(lane>>4)*4+reg
                float hv = fmaxf(acc[reg] + bias, 0.f);
                s4 += (node == 63) ? 0.f : hv;
            }
            s4 += __shfl_xor(s4, 16, 64);
            s4 += __shfl_xor(s4, 32, 64);
            if (g == 0) hpart[mt * 64 + o] = s4;
        }
    }

    // ---- phase 2a: robot layer-2 partials from hoisted wr2 quads ----
    {
        float4 rp = {0.f, 0.f, 0.f, 0.f};
        #pragma unroll
        for (int j = 0; j < 8; ++j) {
            float hv = rrow[fgrp * 8 + j];             // 4-addr broadcast
            rp.x = fmaf(hv, wr2q[j].x, rp.x);
            rp.y = fmaf(hv, wr2q[j].y, rp.y);
            rp.z = fmaf(hv, wr2q[j].z, rp.z);
            rp.w = fmaf(hv, wr2q[j].w, rp.w);
        }
        *(float4*)&rp_lds[fgrp * 64 + o0] = rp;
    }

    // cw loads issued now: ~latency hides under remaining 2b + barrier + ph3
    float4 cwq[4][3];
    #pragma unroll
    for (int ff = 0; ff < 4; ++ff)
        #pragma unroll
        for (int k = 0; k < 3; ++k)
            cwq[ff][k] = *(const float4*)&cw[k * 4096 + (fgrp * 4 + ff) * 64 + o0];
    __syncthreads();                                   // B2

    // ---- phase 3+4 fused: each thread builds its 4 (r,S) values redundantly,
    // then computes its o-quad of the folded-Cheb output matmul.
    {
        const float c1 = 1.0f / 63.0f;
        const float c2 = 2.0f / 3969.0f - 1.0f;
        const float c3 = 124.0f / 3969.0f;
        float4 a4 = {0.f, 0.f, 0.f, 0.f};
        #pragma unroll
        for (int ff = 0; ff < 4; ++ff) {
            int f = fgrp * 4 + ff;
            float rsum = wr2b_l[f];
            #pragma unroll
            for (int kg = 0; kg < 16; ++kg) rsum += rp_lds[kg * 64 + f];
            float rv = fmaxf(rsum, 0.f);
            float sv = rv + hpart[f] + hpart[64 + f] + hpart[128 + f] + hpart[192 + f];
            #pragma unroll
            for (int c = 0; c < 4; ++c) {
                float w0  = (&cwq[ff][0].x)[c];
                float w1  = (&cwq[ff][1].x)[c];
                float w2v = (&cwq[ff][2].x)[c];
                (&a4.x)[c] += rv * (w0 + c1 * w1 + c2 * w2v)
                            + sv * (c3 * w2v - c1 * w1);
            }
        }
        float* out_part = reinterpret_cast<float*>(fragA);   // fragA dead after 2b
        *(float4*)&out_part[fgrp * 64 + o0] = a4;
    }
    __syncthreads();                                   // B3

    if (t < 64) {
        const float* out_part = reinterpret_cast<const float*>(fragA);
        float a = cb_l[t];
        #pragma unroll
        for (int kg = 0; kg < 16; ++kg) a += out_part[kg * 64 + t];
        out[b * 64 + t] = a;
    }
}

extern "C" void kernel_launch(void* const* d_in, const int* in_sizes, int n_in,
                              void* d_out, int out_size, void* d_ws, size_t ws_size,
                              hipStream_t stream) {
    const float* robot_x = (const float*)d_in[0];
    const float* human_x = (const float*)d_in[1];
    // d_in[2] = edge_index (int32) -- fixed complete digraph; unused.
    const float* wr1   = (const float*)d_in[3];
    const float* wr1_b = (const float*)d_in[4];
    const float* wr2   = (const float*)d_in[5];
    const float* wr2_b = (const float*)d_in[6];
    const float* wh1   = (const float*)d_in[7];
    const float* wh1_b = (const float*)d_in[8];
    const float* wh2   = (const float*)d_in[9];
    const float* wh2_b = (const float*)d_in[10];
    const float* cw    = (const float*)d_in[11];
    const float* cb    = (const float*)d_in[12];
    float* out = (float*)d_out;

    dgcrnn_mfma<<<512, BDIM, 0, stream>>>(robot_x, human_x,
                                          wr1, wr1_b, wr2, wr2_b,
                                          wh1, wh1_b, wh2, wh2_b,
                                          cw, cb, out);
}

// Round 7
// 11.445 us; speedup vs baseline: 3.9702x; 1.0462x over previous
//
#include <hip/hip_runtime.h>

// DGCRNN forward, analytically reduced (complete digraph N=64, deg=63):
//   prop(x) = (x - S)/63 with S = column-sum; only robot node kept =>
//   out[b,o] = sum_f r[f]*Ar[f,o] + S[f]*As[f,o] + cb[o]
//   Ar = W0 + W1/63 + (2/3969 - 1)*W2,  As = -W1/63 + (124/3969)*W2
//
// R6 -> R7: LDS-unit pressure halved (~220 -> ~120 DS instr/thread):
// phase-1 weights in registers (global float4, not LDS); wave-level shfl
// pre-reduction for robot/output partials (16 rows -> 4); wh2T staged via
// ds_write_b128; bf16 packing via v_cvt_pk_bf16_f32.

#define BDIM 256

typedef __attribute__((ext_vector_type(8))) short bf16x8;
typedef __attribute__((ext_vector_type(4))) float f32x4;
typedef __attribute__((ext_vector_type(4))) unsigned int u32x4;

static __device__ __forceinline__ unsigned int cvt_pk_bf16(float lo, float hi) {
    unsigned int r;                    // dst.lo16 = bf16(lo) -> memory element 2j
    asm("v_cvt_pk_bf16_f32 %0, %1, %2" : "=v"(r) : "v"(lo), "v"(hi));
    return r;
}

__global__ __launch_bounds__(256, 2) void dgcrnn_mfma(
    const float* __restrict__ robot_x,  // [B,1,9]
    const float* __restrict__ human_x,  // [B,63,5]
    const float* __restrict__ wr1, const float* __restrict__ wr1_b,   // [9,128],[128]
    const float* __restrict__ wr2, const float* __restrict__ wr2_b,   // [128,64],[64]
    const float* __restrict__ wh1, const float* __restrict__ wh1_b,   // [5,128],[128]
    const float* __restrict__ wh2, const float* __restrict__ wh2_b,   // [128,64],[64]
    const float* __restrict__ cw,  const float* __restrict__ cb,      // [3,64,64],[64]
    float* __restrict__ out)                                          // [B,64]
{
    __shared__ float x_lds[324];                       // robot [0..8], humans [63][5]
    __shared__ float wh2b_l[64], wr2b_l[64], cb_l[64];
    __shared__ float rrow[128];                        // robot h1 (fp32)
    __shared__ __align__(16) unsigned int wh2T[4096];  // wh2^T bf16x2, XOR-swizzled
    __shared__ __align__(16) short fragA[8192];        // bf16 A-frags; later out_part
    __shared__ __align__(16) float rp_red[256];        // [4][64] wave-reduced robot l2
    __shared__ float hpart[256];                       // [wave][o] human-sum partials

    const int t    = threadIdx.x;
    const int b    = blockIdx.x;
    const int l    = t & 63;
    const int w    = t >> 6;          // wave 0..3
    const int o0   = (t & 15) * 4;    // o-quad base
    const int fgrp = t >> 4;          // 0..15

    // ---- hoisted register loads (latency hides under staging/B0) ----
    f32x4 wr2q[8];                                     // wr2[fgrp*8+j][o0..+3]
    #pragma unroll
    for (int j = 0; j < 8; ++j)
        wr2q[j] = *(const f32x4*)&wr2[(fgrp * 8 + j) * 64 + o0];

    const int k0 = ((t >> 6) & 3) * 32 + ((t >> 4) & 3) * 8;   // this thread's k-oct
    f32x4 wv4[10], bias4[2];                           // wh1 cols k0..k0+7 + bias
    #pragma unroll
    for (int i = 0; i < 5; ++i) {
        wv4[2 * i]     = *(const f32x4*)&wh1[i * 128 + k0];
        wv4[2 * i + 1] = *(const f32x4*)&wh1[i * 128 + k0 + 4];
    }
    bias4[0] = *(const f32x4*)&wh1_b[k0];
    bias4[1] = *(const f32x4*)&wh1_b[k0 + 4];

    float wr1c[9], wr1bb = 0.f;
    if (t < 128) {                                     // robot layer-1 col t
        #pragma unroll
        for (int i = 0; i < 9; ++i) wr1c[i] = wr1[i * 128 + t];
        wr1bb = wr1_b[t];
    }

    // ---- stage: inputs, small vecs; wh2 -> bf16 transposed swizzled (b128) ----
    for (int i = t; i < 324; i += BDIM)
        x_lds[i] = (i < 9) ? robot_x[b * 9 + i] : human_x[b * 315 + (i - 9)];
    if (t < 64) { wh2b_l[t] = wh2_b[t]; wr2b_l[t] = wr2_b[t]; cb_l[t] = cb[t]; }
    {
        f32x4 e[4], d[4];
        #pragma unroll
        for (int kk = 0; kk < 4; ++kk) {               // k-pairs kp = fgrp*4+kk
            int kp = fgrp * 4 + kk;
            e[kk] = *(const f32x4*)&wh2[(2 * kp) * 64 + o0];
            d[kk] = *(const f32x4*)&wh2[(2 * kp + 1) * 64 + o0];
        }
        #pragma unroll
        for (int c = 0; c < 4; ++c) {
            int o = o0 + c;
            u32x4 vv;
            #pragma unroll
            for (int kk = 0; kk < 4; ++kk) vv[kk] = cvt_pk_bf16(e[kk][c], d[kk][c]);
            // (fgrp*4+kk)^((o&15)<<2) = ((fgrp*4)^((o&15)<<2)) + kk  -> b128 store
            *(u32x4*)&wh2T[o * 64 + ((fgrp * 4) ^ ((o & 15) << 2))] = vv;
        }
    }
    __syncthreads();                                   // B0

    // ---- phase 1: humans layer-1 -> bf16 A-frags (weights in regs) ----
    #pragma unroll
    for (int s = 0; s < 4; ++s) {
        int slot = s * 256 + t;
        int row  = (s << 4) | (t & 15);                // human index, 63 = pad
        u32x4 vv = {0u, 0u, 0u, 0u};
        if (row != 63) {
            float a8[8];
            #pragma unroll
            for (int j = 0; j < 8; ++j) a8[j] = bias4[j >> 2][j & 3];
            #pragma unroll
            for (int i = 0; i < 5; ++i) {
                float xv = x_lds[9 + row * 5 + i];
                #pragma unroll
                for (int j = 0; j < 8; ++j)
                    a8[j] = fmaf(xv, wv4[2 * i + (j >> 2)][j & 3], a8[j]);
            }
            #pragma unroll
            for (int jw = 0; jw < 4; ++jw)
                vv[jw] = cvt_pk_bf16(fmaxf(a8[2 * jw], 0.f), fmaxf(a8[2 * jw + 1], 0.f));
        }
        *(u32x4*)&fragA[slot * 8] = vv;
    }
    if (t < 128) {                                     // robot h1 from hoisted regs
        float a = wr1bb;
        #pragma unroll
        for (int i = 0; i < 9; ++i) a = fmaf(x_lds[i], wr1c[i], a);
        rrow[t] = fmaxf(a, 0.f);
    }
    __syncthreads();                                   // B1

    // ---- phase 2b: humans layer-2 via MFMA (wave = M-tile mt) ----
    {
        const int c = l & 15, g = l >> 4, mt = w;
        bf16x8 af[4];
        #pragma unroll
        for (int kt = 0; kt < 4; ++kt)
            af[kt] = *reinterpret_cast<const bf16x8*>(&fragA[((mt * 4 + kt) * 64 + l) * 8]);
        #pragma unroll
        for (int nt = 0; nt < 4; ++nt) {
            const int o = nt * 16 + c;
            f32x4 acc = {0.f, 0.f, 0.f, 0.f};
            #pragma unroll
            for (int kt = 0; kt < 4; ++kt) {
                int kw0 = kt * 16 + g * 4;
                bf16x8 bfv = *reinterpret_cast<const bf16x8*>(
                    &wh2T[o * 64 + (kw0 ^ (c << 2))]);
                acc = __builtin_amdgcn_mfma_f32_16x16x32_bf16(af[kt], bfv, acc, 0, 0, 0);
            }
            float bias = wh2b_l[o];
            float s4 = 0.f;
            #pragma unroll
            for (int reg = 0; reg < 4; ++reg) {
                int node = mt * 16 + g * 4 + reg;      // C/D: row=(lane>>4)*4+reg
                float hv = fmaxf(acc[reg] + bias, 0.f);
                s4 += (node == 63) ? 0.f : hv;
            }
            s4 += __shfl_xor(s4, 16, 64);
            s4 += __shfl_xor(s4, 32, 64);
            if (g == 0) hpart[mt * 64 + o] = s4;
        }
    }

    // cw loads issued here: latency hides under 2a + B2 wait
    f32x4 cwq[4][3];
    #pragma unroll
    for (int ff = 0; ff < 4; ++ff)
        #pragma unroll
        for (int k = 0; k < 3; ++k)
            cwq[ff][k] = *(const f32x4*)&cw[k * 4096 + (fgrp * 4 + ff) * 64 + o0];

    // ---- phase 2a: robot layer-2, wave-level shfl pre-reduction -> 4 rows ----
    {
        f32x4 rp = {0.f, 0.f, 0.f, 0.f};
        #pragma unroll
        for (int j = 0; j < 8; ++j) {
            float hv = rrow[fgrp * 8 + j];             // 4-addr broadcast
            #pragma unroll
            for (int c = 0; c < 4; ++c) rp[c] = fmaf(hv, wr2q[j][c], rp[c]);
        }
        #pragma unroll
        for (int c = 0; c < 4; ++c) {                  // sum 4 fgrps within wave
            float v = rp[c];
            v += __shfl_xor(v, 16, 64);
            v += __shfl_xor(v, 32, 64);
            rp[c] = v;
        }
        if (l < 16) *(f32x4*)&rp_red[w * 64 + o0] = rp;   // k-chunk w*32..w*32+31
    }
    __syncthreads();                                   // B2

    // ---- phase 3+4 fused: own (r,S) quad + folded-Cheb output matmul ----
    {
        const float c1 = 1.0f / 63.0f;
        const float c2 = 2.0f / 3969.0f - 1.0f;
        const float c3 = 124.0f / 3969.0f;
        f32x4 a4 = {0.f, 0.f, 0.f, 0.f};
        #pragma unroll
        for (int ff = 0; ff < 4; ++ff) {
            int f = fgrp * 4 + ff;
            float rsum = wr2b_l[f] + rp_red[f] + rp_red[64 + f]
                       + rp_red[128 + f] + rp_red[192 + f];
            float rv = fmaxf(rsum, 0.f);
            float sv = rv + hpart[f] + hpart[64 + f] + hpart[128 + f] + hpart[192 + f];
            #pragma unroll
            for (int c = 0; c < 4; ++c) {
                float w0  = cwq[ff][0][c];
                float w1  = cwq[ff][1][c];
                float w2v = cwq[ff][2][c];
                a4[c] += rv * (w0 + c1 * w1 + c2 * w2v) + sv * (c3 * w2v - c1 * w1);
            }
        }
        #pragma unroll
        for (int c = 0; c < 4; ++c) {                  // sum 4 fgrps within wave
            float v = a4[c];
            v += __shfl_xor(v, 16, 64);
            v += __shfl_xor(v, 32, 64);
            a4[c] = v;
        }
        float* out_part = reinterpret_cast<float*>(fragA);   // fragA dead after 2b
        if (l < 16) *(f32x4*)&out_part[w * 64 + o0] = a4;    // f-chunk w*16..w*16+15
    }
    __syncthreads();                                   // B3

    if (t < 64) {
        const float* out_part = reinterpret_cast<const float*>(fragA);
        out[b * 64 + t] = cb_l[t] + out_part[t] + out_part[64 + t]
                        + out_part[128 + t] + out_part[192 + t];
    }
}

extern "C" void kernel_launch(void* const* d_in, const int* in_sizes, int n_in,
                              void* d_out, int out_size, void* d_ws, size_t ws_size,
                              hipStream_t stream) {
    const float* robot_x = (const float*)d_in[0];
    const float* human_x = (const float*)d_in[1];
    // d_in[2] = edge_index (int32) -- fixed complete digraph; unused.
    const float* wr1   = (const float*)d_in[3];
    const float* wr1_b = (const float*)d_in[4];
    const float* wr2   = (const float*)d_in[5];
    const float* wr2_b = (const float*)d_in[6];
    const float* wh1   = (const float*)d_in[7];
    const float* wh1_b = (const float*)d_in[8];
    const float* wh2   = (const float*)d_in[9];
    const float* wh2_b = (const float*)d_in[10];
    const float* cw    = (const float*)d_in[11];
    const float* cb    = (const float*)d_in[12];
    float* out = (float*)d_out;

    dgcrnn_mfma<<<512, BDIM, 0, stream>>>(robot_x, human_x,
                                          wr1, wr1_b, wr2, wr2_b,
                                          wh1, wh1_b, wh2, wh2_b,
                                          cw, cb, out);
}